// Round 1
// baseline (1035.804 us; speedup 1.0000x reference)
//
#include <hip/hip_runtime.h>
#include <hip/hip_bf16.h>
#include <float.h>
#include <math.h>

// MultiScaleReadout — single-pass fused version.
// N=500000 nodes, D=256, G=1024 segments (batch sorted), H=L=128.
// Structure:
//   k_prep  : bf16-transpose w1/lp_w -> [128 cols][256 k]
//   k_fused : one block per segment; stream segment in 48-row chunks.
//             Per chunk: stage x (f32) -> LDS, accumulate mean/max from the
//             load registers; MFMA (bf16 frags converted from f32 LDS) for
//             gate-hidden h and local l; gate row-reduce; ONLINE softmax
//             (running m, denom, rescale) so attention pool needs no second
//             pass over x; att accumulate from f32 LDS; local gelu sums from
//             MFMA accumulators. x is read from HBM exactly once.

typedef __bf16 bf16;
typedef __bf16 bf16x8 __attribute__((ext_vector_type(8)));
typedef float f32x4 __attribute__((ext_vector_type(4)));

#define D 256
#define HDIM 128
#define LDIM 128
#define ROWS 48        // chunk rows (3 x 16 MFMA tiles)
#define XPAD 260       // f32 per LDS row: 256 + 4 pad -> 1040B stride (65x16B, odd) ~2-way conflicts
#define NMT 3

__device__ __forceinline__ float gelu_f(float v) {
    return 0.5f * v * (1.0f + erff(v * 0.70710678118654752f));
}

// ---------------- Kernel 0: prep (weight transpose to bf16) ----------------
__global__ __launch_bounds__(256) void k_prep(const float* __restrict__ w1,
                                              const float* __restrict__ lpw,
                                              bf16* __restrict__ w1T,
                                              bf16* __restrict__ lpT) {
    int t = blockIdx.x * 256 + threadIdx.x;
    if (t < HDIM * D) {
        int n = t >> 8;   // output col
        int k = t & 255;  // k index
        w1T[t] = (bf16)w1[k * HDIM + n];
        lpT[t] = (bf16)lpw[k * LDIM + n];
    }
}

__device__ __forceinline__ int lower_bound_i(const int* a, int n, int v) {
    int lo = 0, hi = n;
    while (lo < hi) { int mid = (lo + hi) >> 1; if (a[mid] < v) lo = mid + 1; else hi = mid; }
    return lo;
}

// ---------------- Kernel 1: fused single-pass readout ----------------
// 256 threads (4 waves). wave w owns output cols [32w,32w+32) of BOTH h and l.
// thread's pool columns: [4*lane, 4*lane+4) (lane = tid&63), rows it*4+wave.
__global__ __launch_bounds__(256, 3) void k_fused(
    const float* __restrict__ x, const int* __restrict__ batch,
    const bf16* __restrict__ w1T, const float* __restrict__ b1,
    const float* __restrict__ w2, const float* __restrict__ b2,
    const bf16* __restrict__ lpT, const float* __restrict__ lpb,
    float* __restrict__ out, int N)
{
    __shared__ float xs[ROWS][XPAD];   // 49.9 KB f32 chunk (full precision for max/att)
    __shared__ float gpart[4][64];     // per-wave gate partials per row
    __shared__ int sse[2];

    const int g    = blockIdx.x;
    const int tid  = threadIdx.x;
    const int wave = tid >> 6;
    const int lane = tid & 63;
    const int quad = lane >> 4;
    const int l16  = lane & 15;

    if (tid == 0) sse[0] = lower_bound_i(batch, N, g);
    if (tid == 1) sse[1] = lower_bound_i(batch, N, g + 1);
    __syncthreads();
    const int start = sse[0], end = sse[1];
    const int cnt = end - start;

    const int c0 = wave * 32 + l16;
    const int c1 = c0 + 16;
    const float b1c0 = b1[c0], b1c1 = b1[c1];
    const float w2c0 = w2[c0], w2c1 = w2[c1];
    const float lb0  = lpb[c0], lb1 = lpb[c1];
    const float b2c  = b2[0];

    // per-thread pool accumulators (cols 4*lane .. 4*lane+3)
    float msum0=0.f, msum1=0.f, msum2=0.f, msum3=0.f;
    float mmax0=-FLT_MAX, mmax1=-FLT_MAX, mmax2=-FLT_MAX, mmax3=-FLT_MAX;
    float asum0=0.f, asum1=0.f, asum2=0.f, asum3=0.f;
    float ls0=0.f, ls1=0.f;
    float m_run = -FLT_MAX, denom = 0.f;   // replicated (identical) in all threads

    const f32x4 zf = {0.f, 0.f, 0.f, 0.f};

    for (int base = start; base < end; base += ROWS) {
        const int vr = min(ROWS, end - base);
        const float* xb = x + (long)base * D + (lane << 2);

        // ---- stage chunk -> LDS f32; mean/max from load registers ----
        if (vr == ROWS) {
            #pragma unroll
            for (int it = 0; it < 12; ++it) {
                const int row = it * 4 + wave;
                const float4 t4 = *(const float4*)(xb + row * D);
                msum0 += t4.x; msum1 += t4.y; msum2 += t4.z; msum3 += t4.w;
                mmax0 = fmaxf(mmax0, t4.x); mmax1 = fmaxf(mmax1, t4.y);
                mmax2 = fmaxf(mmax2, t4.z); mmax3 = fmaxf(mmax3, t4.w);
                f32x4 v; v[0]=t4.x; v[1]=t4.y; v[2]=t4.z; v[3]=t4.w;
                *(f32x4*)(&xs[row][lane << 2]) = v;
            }
        } else {
            #pragma unroll
            for (int it = 0; it < 12; ++it) {
                const int row = it * 4 + wave;   // wave-uniform guard
                f32x4 v = zf;
                if (row < vr) {
                    const float4 t4 = *(const float4*)(xb + row * D);
                    msum0 += t4.x; msum1 += t4.y; msum2 += t4.z; msum3 += t4.w;
                    mmax0 = fmaxf(mmax0, t4.x); mmax1 = fmaxf(mmax1, t4.y);
                    mmax2 = fmaxf(mmax2, t4.z); mmax3 = fmaxf(mmax3, t4.w);
                    v[0]=t4.x; v[1]=t4.y; v[2]=t4.z; v[3]=t4.w;
                }
                *(f32x4*)(&xs[row][lane << 2]) = v;   // zero-pad invalid rows
            }
        }
        __syncthreads();   // bar1: xs ready

        // ---- MFMA: h = x@w1 (gate hidden), l = x@lp_w ----
        f32x4 h0[NMT], h1[NMT], l0[NMT], l1[NMT];
        #pragma unroll
        for (int mt = 0; mt < NMT; ++mt) { h0[mt]=zf; h1[mt]=zf; l0[mt]=zf; l1[mt]=zf; }

        #pragma unroll
        for (int kt = 0; kt < 8; ++kt) {
            const int k0 = kt * 32 + quad * 8;
            const bf16x8 bw0 = *(const bf16x8*)(w1T + c0 * D + k0);
            const bf16x8 bw1 = *(const bf16x8*)(w1T + c1 * D + k0);
            const bf16x8 bp0 = *(const bf16x8*)(lpT + c0 * D + k0);
            const bf16x8 bp1 = *(const bf16x8*)(lpT + c1 * D + k0);
            #pragma unroll
            for (int mt = 0; mt < NMT; ++mt) {
                const float* xp = &xs[mt * 16 + l16][k0];
                const f32x4 fa = *(const f32x4*)(xp);
                const f32x4 fb = *(const f32x4*)(xp + 4);
                bf16x8 a;
                a[0]=(bf16)fa[0]; a[1]=(bf16)fa[1]; a[2]=(bf16)fa[2]; a[3]=(bf16)fa[3];
                a[4]=(bf16)fb[0]; a[5]=(bf16)fb[1]; a[6]=(bf16)fb[2]; a[7]=(bf16)fb[3];
                h0[mt] = __builtin_amdgcn_mfma_f32_16x16x32_bf16(a, bw0, h0[mt], 0, 0, 0);
                h1[mt] = __builtin_amdgcn_mfma_f32_16x16x32_bf16(a, bw1, h1[mt], 0, 0, 0);
                l0[mt] = __builtin_amdgcn_mfma_f32_16x16x32_bf16(a, bp0, l0[mt], 0, 0, 0);
                l1[mt] = __builtin_amdgcn_mfma_f32_16x16x32_bf16(a, bp1, l1[mt], 0, 0, 0);
            }
        }

        // ---- gate row partials: gelu(h + b1) * w2, reduce over this wave's 32 cols ----
        #pragma unroll
        for (int mt = 0; mt < NMT; ++mt) {
            #pragma unroll
            for (int r = 0; r < 4; ++r) {
                float v = gelu_f(h0[mt][r] + b1c0) * w2c0
                        + gelu_f(h1[mt][r] + b1c1) * w2c1;
                v += __shfl_down(v, 8, 16);
                v += __shfl_down(v, 4, 16);
                v += __shfl_down(v, 2, 16);
                v += __shfl_down(v, 1, 16);
                if (l16 == 0) gpart[wave][mt * 16 + quad * 4 + r] = v;
            }
        }
        __syncthreads();   // bar2: gpart ready

        // ---- online softmax chunk stats (computed redundantly in every wave) ----
        float gv = -FLT_MAX;
        if (lane < vr)
            gv = gpart[0][lane] + gpart[1][lane] + gpart[2][lane] + gpart[3][lane] + b2c;
        float cm = gv;
        #pragma unroll
        for (int off = 32; off > 0; off >>= 1) cm = fmaxf(cm, __shfl_xor(cm, off));
        const float m_new = fmaxf(m_run, cm);
        const float fr = expf(m_run - m_new);          // rescale (0 on first chunk)
        const float ew = (lane < vr) ? expf(gv - m_new) : 0.f;  // e for row=lane
        float se = ew;
        #pragma unroll
        for (int off = 32; off > 0; off >>= 1) se += __shfl_xor(se, off);
        denom = denom * fr + se;
        m_run = m_new;

        // ---- local pool sums (register-only, from MFMA accumulators) ----
        if (vr == ROWS) {
            #pragma unroll
            for (int mt = 0; mt < NMT; ++mt)
                #pragma unroll
                for (int r = 0; r < 4; ++r) {
                    ls0 += gelu_f(l0[mt][r] + lb0);
                    ls1 += gelu_f(l1[mt][r] + lb1);
                }
        } else {
            #pragma unroll
            for (int mt = 0; mt < NMT; ++mt)
                #pragma unroll
                for (int r = 0; r < 4; ++r) {
                    if (mt * 16 + quad * 4 + r < vr) {
                        ls0 += gelu_f(l0[mt][r] + lb0);
                        ls1 += gelu_f(l1[mt][r] + lb1);
                    }
                }
        }

        // ---- attention accumulate: asum = asum*fr + sum_r e_r * x[r] ----
        asum0 *= fr; asum1 *= fr; asum2 *= fr; asum3 *= fr;
        #pragma unroll
        for (int it = 0; it < 12; ++it) {
            const int row = it * 4 + wave;
            const float e = __shfl(ew, row);           // e lives in lane==row
            const f32x4 v = *(const f32x4*)(&xs[row][lane << 2]);
            asum0 += e * v[0]; asum1 += e * v[1];
            asum2 += e * v[2]; asum3 += e * v[3];
        }
        __syncthreads();   // bar3: xs free for next chunk's stage
    }

    // ---------------- epilogue ----------------
    ls0 += __shfl_xor(ls0, 16); ls0 += __shfl_xor(ls0, 32);
    ls1 += __shfl_xor(ls1, 16); ls1 += __shfl_xor(ls1, 32);

    const float inv  = 1.0f / fmaxf((float)cnt, 1.0f);
    const float invd = (denom > 0.f) ? 1.0f / denom : 0.f;
    const long  o    = (long)g * 896;

    // cross-wave reduce via LDS (reuse xs; all reads done at final barrier)
    float* red = &xs[0][0];
    const int cb = (wave << 8) + (lane << 2);
    red[cb]        = msum0; red[cb+1]        = msum1; red[cb+2]        = msum2; red[cb+3]        = msum3;
    red[1024 + cb] = asum0; red[1024 + cb+1] = asum1; red[1024 + cb+2] = asum2; red[1024 + cb+3] = asum3;
    red[2048 + cb] = mmax0; red[2048 + cb+1] = mmax1; red[2048 + cb+2] = mmax2; red[2048 + cb+3] = mmax3;
    if (quad == 0) {
        out[o + 768 + c0] = ls0 * inv;
        out[o + 768 + c1] = ls1 * inv;
    }
    __syncthreads();
    {
        const int col = tid;
        const float s = red[col]        + red[256 + col]  + red[512 + col]  + red[768 + col];
        const float a = red[1024 + col] + red[1280 + col] + red[1536 + col] + red[1792 + col];
        float mm = fmaxf(fmaxf(red[2048 + col], red[2304 + col]),
                         fmaxf(red[2560 + col], red[2816 + col]));
        if (cnt == 0) mm = -INFINITY;
        out[o + col]       = s * inv;
        out[o + 256 + col] = mm;
        out[o + 512 + col] = a * invd;
    }
}

// ---------------- launch ----------------
extern "C" void kernel_launch(void* const* d_in, const int* in_sizes, int n_in,
                              void* d_out, int out_size, void* d_ws, size_t ws_size,
                              hipStream_t stream) {
    const float* x   = (const float*)d_in[0];
    const int* batch = (const int*)d_in[1];
    const float* w1  = (const float*)d_in[2];
    const float* b1  = (const float*)d_in[3];
    const float* w2  = (const float*)d_in[4];
    const float* b2  = (const float*)d_in[5];
    const float* lpw = (const float*)d_in[6];
    const float* lpb = (const float*)d_in[7];
    float* out = (float*)d_out;

    const int N = in_sizes[0] / D;
    const int G = out_size / 896;

    char* ws = (char*)d_ws;
    bf16* w1T = (bf16*)ws;
    bf16* lpT = (bf16*)(ws + (size_t)HDIM * D * sizeof(bf16));

    k_prep<<<(HDIM * D + 255) / 256, 256, 0, stream>>>(w1, lpw, w1T, lpT);
    k_fused<<<G, 256, 0, stream>>>(x, batch, w1T, b1, w2, b2, lpT, lpb, out, N);
}